// Round 3
// baseline (2180.700 us; speedup 1.0000x reference)
//
#include <hip/hip_runtime.h>
#include <hip/hip_bf16.h>

typedef unsigned short u16;
typedef __bf16 bf16x8 __attribute__((ext_vector_type(8)));
typedef float f32x4 __attribute__((ext_vector_type(4)));

#define E_ 8
#define H_ 2048
#define D_ 2048
#define T_ 2048
#define N2_ 4096

__device__ __forceinline__ u16 f2bf(float f) {
    unsigned u = __builtin_bit_cast(unsigned, f);
    unsigned r = (u + 0x7FFFu + ((u >> 16) & 1u)) >> 16;
    return (u16)r;
}

typedef __attribute__((address_space(1))) const void* gptr_t;
typedef __attribute__((address_space(3))) void* lptr_t;
__device__ __forceinline__ void gload16(const void* g, void* l) {
    // async global->LDS, 16B/lane; LDS dest = wave-uniform base + lane*16
    __builtin_amdgcn_global_load_lds((gptr_t)g, (lptr_t)l, 16, 0, 0);
}

// LDS tile layout (BK=64): 128 rows x 64 u16 (128B = 8 chunks of 16B).
// Physical chunk(r,c) stored at c ^ (r&7)  -> every ds_read_b128 fragment
// access is exactly 2-way bank-aliased (free, m136). The swizzle is applied
// by permuting the global SOURCE address per lane during global_load_lds
// (dest order is fixed: base + lane*16).

// ---------------- conversion / transpose pre-pass ----------------

__global__ __launch_bounds__(256) void k_convert_x(const float4* __restrict__ x,
                                                   ushort4* __restrict__ xb) {
    int i = blockIdx.x * 256 + threadIdx.x;   // exactly T_*H_/4 threads
    float4 v = x[i];
    ushort4 o;
    o.x = f2bf(v.x); o.y = f2bf(v.y); o.z = f2bf(v.z); o.w = f2bf(v.w);
    xb[i] = o;
}

// gate_up_w fp32 [E][H][2D] -> wgT,wuT bf16 [E][D][H]  (transpose + de-interleave)
__global__ __launch_bounds__(256) void k_tr_gateup(const float* __restrict__ w,
                                                   u16* __restrict__ wgT,
                                                   u16* __restrict__ wuT) {
    __shared__ u16 Gs[64 * 73];
    __shared__ u16 Us[64 * 73];
    const int e = blockIdx.z, h0 = blockIdx.x * 64, d0 = blockIdx.y * 64;
    const int tid = threadIdx.x;
    {
        const int hl = tid >> 2;               // 0..63
        const int cseg = (tid & 3) * 32;       // fp32 col offset within 128
        const float* src = w + ((size_t)e * H_ + h0 + hl) * N2_ + 2 * d0 + cseg;
#pragma unroll
        for (int q = 0; q < 8; q++) {
            float4 v = *(const float4*)(src + q * 4);
            int dl = (cseg + q * 4) >> 1;      // even
            Gs[hl * 73 + dl]     = f2bf(v.x);
            Us[hl * 73 + dl]     = f2bf(v.y);
            Gs[hl * 73 + dl + 1] = f2bf(v.z);
            Us[hl * 73 + dl + 1] = f2bf(v.w);
        }
    }
    __syncthreads();
    {
        const int dl = tid >> 2;
        const int hseg = (tid & 3) * 16;
        u16 vg[16] __attribute__((aligned(16)));
        u16 vu[16] __attribute__((aligned(16)));
#pragma unroll
        for (int j = 0; j < 16; j++) {
            vg[j] = Gs[(hseg + j) * 73 + dl];
            vu[j] = Us[(hseg + j) * 73 + dl];
        }
        size_t ob = ((size_t)e * D_ + d0 + dl) * H_ + h0 + hseg;
        *(uint4*)&wgT[ob]     = *(const uint4*)&vg[0];
        *(uint4*)&wgT[ob + 8] = *(const uint4*)&vg[8];
        *(uint4*)&wuT[ob]     = *(const uint4*)&vu[0];
        *(uint4*)&wuT[ob + 8] = *(const uint4*)&vu[8];
    }
}

// down_w fp32 [E][D][H] -> wdT bf16 [E][H][D]  (transpose)
__global__ __launch_bounds__(256) void k_tr_down(const float* __restrict__ w,
                                                 u16* __restrict__ wdT) {
    __shared__ u16 Ts[64 * 73];
    const int e = blockIdx.z, d0 = blockIdx.x * 64, h0 = blockIdx.y * 64;
    const int tid = threadIdx.x;
    {
        const int dl = tid >> 2;
        const int hseg = (tid & 3) * 16;
        const float* src = w + ((size_t)e * D_ + d0 + dl) * H_ + h0 + hseg;
#pragma unroll
        for (int q = 0; q < 4; q++) {
            float4 v = *(const float4*)(src + q * 4);
            int hl = hseg + q * 4;
            Ts[(hl + 0) * 73 + dl] = f2bf(v.x);
            Ts[(hl + 1) * 73 + dl] = f2bf(v.y);
            Ts[(hl + 2) * 73 + dl] = f2bf(v.z);
            Ts[(hl + 3) * 73 + dl] = f2bf(v.w);
        }
    }
    __syncthreads();
    {
        const int hl = tid >> 2;
        const int dseg = (tid & 3) * 16;
        u16 vd[16] __attribute__((aligned(16)));
#pragma unroll
        for (int j = 0; j < 16; j++) vd[j] = Ts[hl * 73 + dseg + j];
        size_t ob = ((size_t)e * H_ + h0 + hl) * D_ + d0 + dseg;
        *(uint4*)&wdT[ob]     = *(const uint4*)&vd[0];
        *(uint4*)&wdT[ob + 8] = *(const uint4*)&vd[8];
    }
}

// ---------------- GEMM 1: gate_up + GLU epilogue (rw folded in) ----------------
// fused[e][t][d] = rw[t][e] * (clip(up,-7,7)+1) * glu(min(gate,7))

__global__ __launch_bounds__(256, 3) void k_gemm_gateup(
    const u16* __restrict__ xb,    // [T][H] bf16
    const u16* __restrict__ wgT,   // [E][D][H] bf16
    const u16* __restrict__ wuT,   // [E][D][H] bf16
    const float* __restrict__ gub, // [E][2D] fp32 interleaved
    const float* __restrict__ rw,  // [T][E] fp32
    u16* __restrict__ fused)       // [E][T][D] bf16
{
    const int e = blockIdx.z;
    const int t0 = blockIdx.x * 128;
    const int d0 = blockIdx.y * 128;
    __shared__ u16 As[128 * 64];
    __shared__ u16 Bgs[128 * 64];
    __shared__ u16 Bus[128 * 64];

    const int tid = threadIdx.x;
    const int lane = tid & 63;
    const int wave = tid >> 6;
    const int wr = (wave >> 1) * 64;
    const int wc = (wave & 1) * 64;
    const int l16 = lane & 15;
    const int quad = lane >> 4;

    f32x4 accg[4][4], accu[4][4];
    const f32x4 vzero = {0.f, 0.f, 0.f, 0.f};
#pragma unroll
    for (int i = 0; i < 4; i++)
#pragma unroll
        for (int j = 0; j < 4; j++) { accg[i][j] = vzero; accu[i][j] = vzero; }

    const u16* Ag  = xb + (size_t)t0 * H_;
    const u16* Bgg = wgT + ((size_t)e * D_ + d0) * H_;
    const u16* Bug = wuT + ((size_t)e * D_ + d0) * H_;

    // staging: one gload16 covers 8 rows x 64 u16; lane -> row R+ (lane>>3),
    // physical chunk lane&7; source chunk = (lane&7) ^ (lane>>3)  [swizzle]
    const int sr = lane >> 3;
    const int csrc = ((lane & 7) ^ sr) * 8;   // u16 offset in row

    for (int k0 = 0; k0 < H_; k0 += 64) {
#pragma unroll
        for (int c = 0; c < 4; c++) {
            const int R = wave * 32 + c * 8;
            const size_t go = (size_t)(R + sr) * H_ + k0 + csrc;
            gload16(Ag + go,  &As[R * 64]);
            gload16(Bgg + go, &Bgs[R * 64]);
            gload16(Bug + go, &Bus[R * 64]);
        }
        __syncthreads();
#pragma unroll
        for (int kk = 0; kk < 2; kk++) {
            // fragment col (u16): physical chunk = (kk*4+quad) ^ (row&7); row&7 == l16&7
            const int pco = (((kk << 2) | quad) ^ (l16 & 7)) * 8;
            bf16x8 af[4], bg[4], bu[4];
#pragma unroll
            for (int i = 0; i < 4; i++)
                af[i] = *(const bf16x8*)&As[(wr + i * 16 + l16) * 64 + pco];
#pragma unroll
            for (int j = 0; j < 4; j++) {
                bg[j] = *(const bf16x8*)&Bgs[(wc + j * 16 + l16) * 64 + pco];
                bu[j] = *(const bf16x8*)&Bus[(wc + j * 16 + l16) * 64 + pco];
            }
#pragma unroll
            for (int i = 0; i < 4; i++)
#pragma unroll
                for (int j = 0; j < 4; j++) {
                    accg[i][j] = __builtin_amdgcn_mfma_f32_16x16x32_bf16(af[i], bg[j], accg[i][j], 0, 0, 0);
                    accu[i][j] = __builtin_amdgcn_mfma_f32_16x16x32_bf16(af[i], bu[j], accu[i][j], 0, 0, 0);
                }
        }
        __syncthreads();
    }

    // epilogue: bias + clamp + GLU, scale by routing weight, write bf16
#pragma unroll
    for (int j = 0; j < 4; j++) {
        const int col = d0 + wc + j * 16 + l16;
        const float bgv = gub[e * N2_ + 2 * col];
        const float buv = gub[e * N2_ + 2 * col + 1];
#pragma unroll
        for (int i = 0; i < 4; i++) {
#pragma unroll
            for (int r = 0; r < 4; r++) {
                int row = t0 + wr + i * 16 + quad * 4 + r;
                float g = accg[i][j][r] + bgv;
                float u = accu[i][j][r] + buv;
                g = fminf(g, 7.0f);
                u = fminf(fmaxf(u, -7.0f), 7.0f);
                float glu = g / (1.0f + __expf(-1.702f * g));
                float f = (u + 1.0f) * glu * rw[row * E_ + e];
                fused[((size_t)e * T_ + row) * D_ + col] = f2bf(f);
            }
        }
    }
}

// ---------------- GEMM 2: down proj, experts-in-K, 128x256 tile, no atomics ----
// pout[g][t][h] = sum_{e in pair g} fused[e][t][:] @ wdT[e][h][:]

__global__ __launch_bounds__(256, 3) void k_gemm_down(
    const u16* __restrict__ fused, // [E][T][D] bf16 (rw-scaled)
    const u16* __restrict__ wdT,   // [E][H][D] bf16
    float* __restrict__ pout)      // [4][T][H] fp32 partials
{
    const int g = blockIdx.z;          // expert pair: experts 2g, 2g+1
    const int t0 = blockIdx.x * 128;
    const int h0 = blockIdx.y * 256;
    __shared__ u16 As[128 * 64];
    __shared__ u16 B0s[128 * 64];
    __shared__ u16 B1s[128 * 64];

    const int tid = threadIdx.x;
    const int lane = tid & 63;
    const int wave = tid >> 6;
    const int wr = (wave >> 1) * 64;
    const int wc = (wave & 1) * 64;
    const int l16 = lane & 15;
    const int quad = lane >> 4;

    f32x4 acc0[4][4], acc1[4][4];
    const f32x4 vzero = {0.f, 0.f, 0.f, 0.f};
#pragma unroll
    for (int i = 0; i < 4; i++)
#pragma unroll
        for (int j = 0; j < 4; j++) { acc0[i][j] = vzero; acc1[i][j] = vzero; }

    const int sr = lane >> 3;
    const int csrc = ((lane & 7) ^ sr) * 8;

    for (int ee = 0; ee < 2; ee++) {
        const int e = g * 2 + ee;
        const u16* Ag  = fused + ((size_t)e * T_ + t0) * D_;
        const u16* Bg0 = wdT + ((size_t)e * H_ + h0) * D_;
        const u16* Bg1 = wdT + ((size_t)e * H_ + h0 + 128) * D_;
        for (int k0 = 0; k0 < D_; k0 += 64) {
#pragma unroll
            for (int c = 0; c < 4; c++) {
                const int R = wave * 32 + c * 8;
                const size_t go = (size_t)(R + sr) * D_ + k0 + csrc;
                gload16(Ag + go,  &As[R * 64]);
                gload16(Bg0 + go, &B0s[R * 64]);
                gload16(Bg1 + go, &B1s[R * 64]);
            }
            __syncthreads();
#pragma unroll
            for (int kk = 0; kk < 2; kk++) {
                const int pco = (((kk << 2) | quad) ^ (l16 & 7)) * 8;
                bf16x8 af[4], b0[4], b1[4];
#pragma unroll
                for (int i = 0; i < 4; i++)
                    af[i] = *(const bf16x8*)&As[(wr + i * 16 + l16) * 64 + pco];
#pragma unroll
                for (int j = 0; j < 4; j++) {
                    b0[j] = *(const bf16x8*)&B0s[(wc + j * 16 + l16) * 64 + pco];
                    b1[j] = *(const bf16x8*)&B1s[(wc + j * 16 + l16) * 64 + pco];
                }
#pragma unroll
                for (int i = 0; i < 4; i++)
#pragma unroll
                    for (int j = 0; j < 4; j++) {
                        acc0[i][j] = __builtin_amdgcn_mfma_f32_16x16x32_bf16(af[i], b0[j], acc0[i][j], 0, 0, 0);
                        acc1[i][j] = __builtin_amdgcn_mfma_f32_16x16x32_bf16(af[i], b1[j], acc1[i][j], 0, 0, 0);
                    }
            }
            __syncthreads();
        }
    }

    float* po = pout + (size_t)g * T_ * H_;
#pragma unroll
    for (int i = 0; i < 4; i++) {
#pragma unroll
        for (int r = 0; r < 4; r++) {
            int row = t0 + wr + i * 16 + quad * 4 + r;
#pragma unroll
            for (int j = 0; j < 4; j++) {
                int col0 = h0 + wc + j * 16 + l16;
                po[(size_t)row * H_ + col0]       = acc0[i][j][r];
                po[(size_t)row * H_ + col0 + 128] = acc1[i][j][r];
            }
        }
    }
}

// out[t][h] = sum_g pout[g] + sum_e rw[t][e] * down_b[e][h]
__global__ __launch_bounds__(256) void k_combine(const float* __restrict__ p,
                                                 const float* __restrict__ rw,
                                                 const float* __restrict__ db,
                                                 float* __restrict__ out) {
    int idx = blockIdx.x * 256 + threadIdx.x;  // exactly T_*H_ threads
    int t = idx >> 11;
    int h = idx & (H_ - 1);
    const size_t TH = (size_t)T_ * H_;
    float s = p[idx] + p[idx + TH] + p[idx + 2 * TH] + p[idx + 3 * TH];
#pragma unroll
    for (int e = 0; e < E_; e++) s += rw[t * E_ + e] * db[e * H_ + h];
    out[idx] = s;
}

// ---------------- launch ----------------

extern "C" void kernel_launch(void* const* d_in, const int* in_sizes, int n_in,
                              void* d_out, int out_size, void* d_ws, size_t ws_size,
                              hipStream_t stream) {
    const float* x   = (const float*)d_in[0];   // [B,S,H]
    const float* rw  = (const float*)d_in[1];   // [T,E]
    const float* guw = (const float*)d_in[2];   // [E,H,2D]
    const float* gub = (const float*)d_in[3];   // [E,2D]
    const float* dww = (const float*)d_in[4];   // [E,D,H]
    const float* dwb = (const float*)d_in[5];   // [E,H]
    float* out = (float*)d_out;

    char* ws = (char*)d_ws;
    u16* xb    = (u16*)(ws);                      //  8 MB  [T][H]
    u16* wgT   = (u16*)(ws + 8388608);            // 64 MB  [E][D][H]
    u16* wuT   = (u16*)(ws + 75497472);           // 64 MB  [E][D][H]
    u16* wdT   = (u16*)(ws + 142606336);          // 64 MB  [E][H][D]
    u16* fused = (u16*)(ws + 209715200);          // 64 MB  [E][T][D]
    // pout (64 MB fp32 [4][T][H]) reuses the wgT region — wgT is dead after
    // k_gemm_gateup, and the stream serializes gateup -> down -> combine.
    float* pout = (float*)(ws + 8388608);

    k_convert_x<<<dim3((T_ * H_) / 4 / 256), 256, 0, stream>>>((const float4*)x, (ushort4*)xb);
    k_tr_gateup<<<dim3(H_ / 64, D_ / 64, E_), 256, 0, stream>>>(guw, wgT, wuT);
    k_tr_down<<<dim3(D_ / 64, H_ / 64, E_), 256, 0, stream>>>(dww, wdT);
    k_gemm_gateup<<<dim3(T_ / 128, D_ / 128, E_), 256, 0, stream>>>(xb, wgT, wuT, gub, rw, fused);
    k_gemm_down<<<dim3(T_ / 128, H_ / 256, 4), 256, 0, stream>>>(fused, wdT, pout);
    k_combine<<<dim3((T_ * H_) / 256), 256, 0, stream>>>(pout, rw, dwb, out);
}

// Round 4
// 914.884 us; speedup vs baseline: 2.3836x; 2.3836x over previous
//
#include <hip/hip_runtime.h>
#include <hip/hip_bf16.h>

typedef unsigned short u16;
typedef __bf16 bf16x8 __attribute__((ext_vector_type(8)));
typedef float f32x4 __attribute__((ext_vector_type(4)));

#define E_ 8
#define H_ 2048
#define D_ 2048
#define T_ 2048
#define N2_ 4096

__device__ __forceinline__ u16 f2bf(float f) {
    unsigned u = __builtin_bit_cast(unsigned, f);
    unsigned r = (u + 0x7FFFu + ((u >> 16) & 1u)) >> 16;
    return (u16)r;
}

typedef __attribute__((address_space(1))) const void* gptr_t;
typedef __attribute__((address_space(3))) void* lptr_t;
__device__ __forceinline__ void gload16(const void* g, void* l) {
    // async global->LDS, 16B/lane; LDS dest = wave-uniform base + lane*16
    __builtin_amdgcn_global_load_lds((gptr_t)g, (lptr_t)l, 16, 0, 0);
}

// LDS tile layout (BK=64): 128 rows x 64 u16 (128B = 8 chunks of 16B).
// Physical chunk(r,c) stored at c ^ (r&7)  -> every ds_read_b128 fragment
// access is exactly 2-way bank-aliased (free, m136; verified R3: conflicts=0).
// Swizzle applied by permuting the global SOURCE address per lane during
// global_load_lds (dest order is fixed: base + lane*16).
//
// NOTE (R3 post-mortem): __launch_bounds__(256,3) caps VGPRs at ~170 and
// spills the 128-reg accumulator tile -> 1.5 GB scratch WRITE traffic, 3x
// slowdown. This kernel family requires the 2-wave/EU register budget.

// ---------------- conversion / transpose pre-pass ----------------

__global__ __launch_bounds__(256) void k_convert_x(const float4* __restrict__ x,
                                                   ushort4* __restrict__ xb) {
    int i = blockIdx.x * 256 + threadIdx.x;   // exactly T_*H_/4 threads
    float4 v = x[i];
    ushort4 o;
    o.x = f2bf(v.x); o.y = f2bf(v.y); o.z = f2bf(v.z); o.w = f2bf(v.w);
    xb[i] = o;
}

// gate_up_w fp32 [E][H][2D] -> wgT,wuT bf16 [E][D][H]  (transpose + de-interleave)
__global__ __launch_bounds__(256) void k_tr_gateup(const float* __restrict__ w,
                                                   u16* __restrict__ wgT,
                                                   u16* __restrict__ wuT) {
    __shared__ u16 Gs[64 * 73];
    __shared__ u16 Us[64 * 73];
    const int e = blockIdx.z, h0 = blockIdx.x * 64, d0 = blockIdx.y * 64;
    const int tid = threadIdx.x;
    {
        const int hl = tid >> 2;               // 0..63
        const int cseg = (tid & 3) * 32;       // fp32 col offset within 128
        const float* src = w + ((size_t)e * H_ + h0 + hl) * N2_ + 2 * d0 + cseg;
#pragma unroll
        for (int q = 0; q < 8; q++) {
            float4 v = *(const float4*)(src + q * 4);
            int dl = (cseg + q * 4) >> 1;      // even
            Gs[hl * 73 + dl]     = f2bf(v.x);
            Us[hl * 73 + dl]     = f2bf(v.y);
            Gs[hl * 73 + dl + 1] = f2bf(v.z);
            Us[hl * 73 + dl + 1] = f2bf(v.w);
        }
    }
    __syncthreads();
    {
        const int dl = tid >> 2;
        const int hseg = (tid & 3) * 16;
        u16 vg[16] __attribute__((aligned(16)));
        u16 vu[16] __attribute__((aligned(16)));
#pragma unroll
        for (int j = 0; j < 16; j++) {
            vg[j] = Gs[(hseg + j) * 73 + dl];
            vu[j] = Us[(hseg + j) * 73 + dl];
        }
        size_t ob = ((size_t)e * D_ + d0 + dl) * H_ + h0 + hseg;
        *(uint4*)&wgT[ob]     = *(const uint4*)&vg[0];
        *(uint4*)&wgT[ob + 8] = *(const uint4*)&vg[8];
        *(uint4*)&wuT[ob]     = *(const uint4*)&vu[0];
        *(uint4*)&wuT[ob + 8] = *(const uint4*)&vu[8];
    }
}

// down_w fp32 [E][D][H] -> wdT bf16 [E][H][D]  (transpose)
__global__ __launch_bounds__(256) void k_tr_down(const float* __restrict__ w,
                                                 u16* __restrict__ wdT) {
    __shared__ u16 Ts[64 * 73];
    const int e = blockIdx.z, d0 = blockIdx.x * 64, h0 = blockIdx.y * 64;
    const int tid = threadIdx.x;
    {
        const int dl = tid >> 2;
        const int hseg = (tid & 3) * 16;
        const float* src = w + ((size_t)e * D_ + d0 + dl) * H_ + h0 + hseg;
#pragma unroll
        for (int q = 0; q < 4; q++) {
            float4 v = *(const float4*)(src + q * 4);
            int hl = hseg + q * 4;
            Ts[(hl + 0) * 73 + dl] = f2bf(v.x);
            Ts[(hl + 1) * 73 + dl] = f2bf(v.y);
            Ts[(hl + 2) * 73 + dl] = f2bf(v.z);
            Ts[(hl + 3) * 73 + dl] = f2bf(v.w);
        }
    }
    __syncthreads();
    {
        const int hl = tid >> 2;
        const int dseg = (tid & 3) * 16;
        u16 vd[16] __attribute__((aligned(16)));
#pragma unroll
        for (int j = 0; j < 16; j++) vd[j] = Ts[hl * 73 + dseg + j];
        size_t ob = ((size_t)e * H_ + h0 + hl) * D_ + d0 + dseg;
        *(uint4*)&wdT[ob]     = *(const uint4*)&vd[0];
        *(uint4*)&wdT[ob + 8] = *(const uint4*)&vd[8];
    }
}

// ---------------- GEMM 1: gate_up + GLU epilogue (rw folded in) ----------------
// fused[e][t][d] = rw[t][e] * (clip(up,-7,7)+1) * glu(min(gate,7))

__global__ __launch_bounds__(256, 2) void k_gemm_gateup(
    const u16* __restrict__ xb,    // [T][H] bf16
    const u16* __restrict__ wgT,   // [E][D][H] bf16
    const u16* __restrict__ wuT,   // [E][D][H] bf16
    const float* __restrict__ gub, // [E][2D] fp32 interleaved
    const float* __restrict__ rw,  // [T][E] fp32
    u16* __restrict__ fused)       // [E][T][D] bf16
{
    const int e = blockIdx.z;
    const int t0 = blockIdx.x * 128;
    const int d0 = blockIdx.y * 128;
    __shared__ u16 As[128 * 64];
    __shared__ u16 Bgs[128 * 64];
    __shared__ u16 Bus[128 * 64];

    const int tid = threadIdx.x;
    const int lane = tid & 63;
    const int wave = tid >> 6;
    const int wr = (wave >> 1) * 64;
    const int wc = (wave & 1) * 64;
    const int l16 = lane & 15;
    const int quad = lane >> 4;

    f32x4 accg[4][4], accu[4][4];
    const f32x4 vzero = {0.f, 0.f, 0.f, 0.f};
#pragma unroll
    for (int i = 0; i < 4; i++)
#pragma unroll
        for (int j = 0; j < 4; j++) { accg[i][j] = vzero; accu[i][j] = vzero; }

    const u16* Ag  = xb + (size_t)t0 * H_;
    const u16* Bgg = wgT + ((size_t)e * D_ + d0) * H_;
    const u16* Bug = wuT + ((size_t)e * D_ + d0) * H_;

    // staging: one gload16 covers 8 rows x 64 u16; lane -> row R+(lane>>3),
    // physical chunk lane&7; source chunk = (lane&7) ^ (lane>>3)  [swizzle]
    const int sr = lane >> 3;
    const int csrc = ((lane & 7) ^ sr) * 8;   // u16 offset in row

    for (int k0 = 0; k0 < H_; k0 += 64) {
#pragma unroll
        for (int c = 0; c < 4; c++) {
            const int R = wave * 32 + c * 8;
            const size_t go = (size_t)(R + sr) * H_ + k0 + csrc;
            gload16(Ag + go,  &As[R * 64]);
            gload16(Bgg + go, &Bgs[R * 64]);
            gload16(Bug + go, &Bus[R * 64]);
        }
        __syncthreads();
#pragma unroll
        for (int kk = 0; kk < 2; kk++) {
            // fragment col (u16): physical chunk = (kk*4+quad) ^ (row&7); row&7 == l16&7
            const int pco = (((kk << 2) | quad) ^ (l16 & 7)) * 8;
            bf16x8 af[4], bg[4], bu[4];
#pragma unroll
            for (int i = 0; i < 4; i++)
                af[i] = *(const bf16x8*)&As[(wr + i * 16 + l16) * 64 + pco];
#pragma unroll
            for (int j = 0; j < 4; j++) {
                bg[j] = *(const bf16x8*)&Bgs[(wc + j * 16 + l16) * 64 + pco];
                bu[j] = *(const bf16x8*)&Bus[(wc + j * 16 + l16) * 64 + pco];
            }
#pragma unroll
            for (int i = 0; i < 4; i++)
#pragma unroll
                for (int j = 0; j < 4; j++) {
                    accg[i][j] = __builtin_amdgcn_mfma_f32_16x16x32_bf16(af[i], bg[j], accg[i][j], 0, 0, 0);
                    accu[i][j] = __builtin_amdgcn_mfma_f32_16x16x32_bf16(af[i], bu[j], accu[i][j], 0, 0, 0);
                }
        }
        __syncthreads();
    }

    // epilogue: bias + clamp + GLU, scale by routing weight, write bf16
#pragma unroll
    for (int j = 0; j < 4; j++) {
        const int col = d0 + wc + j * 16 + l16;
        const float bgv = gub[e * N2_ + 2 * col];
        const float buv = gub[e * N2_ + 2 * col + 1];
#pragma unroll
        for (int i = 0; i < 4; i++) {
#pragma unroll
            for (int r = 0; r < 4; r++) {
                int row = t0 + wr + i * 16 + quad * 4 + r;
                float g = accg[i][j][r] + bgv;
                float u = accu[i][j][r] + buv;
                g = fminf(g, 7.0f);
                u = fminf(fmaxf(u, -7.0f), 7.0f);
                float glu = g / (1.0f + __expf(-1.702f * g));
                float f = (u + 1.0f) * glu * rw[row * E_ + e];
                fused[((size_t)e * T_ + row) * D_ + col] = f2bf(f);
            }
        }
    }
}

// ---------------- GEMM 2: down proj, experts-in-K, 128x256 tile, no atomics ----
// pout[g][t][h] = sum_{e in pair g} fused[e][t][:] @ wdT[e][h][:]

__global__ __launch_bounds__(256, 2) void k_gemm_down(
    const u16* __restrict__ fused, // [E][T][D] bf16 (rw-scaled)
    const u16* __restrict__ wdT,   // [E][H][D] bf16
    float* __restrict__ pout)      // [4][T][H] fp32 partials
{
    const int g = blockIdx.z;          // expert pair: experts 2g, 2g+1
    const int t0 = blockIdx.x * 128;
    const int h0 = blockIdx.y * 256;
    __shared__ u16 As[128 * 64];
    __shared__ u16 B0s[128 * 64];
    __shared__ u16 B1s[128 * 64];

    const int tid = threadIdx.x;
    const int lane = tid & 63;
    const int wave = tid >> 6;
    const int wr = (wave >> 1) * 64;
    const int wc = (wave & 1) * 64;
    const int l16 = lane & 15;
    const int quad = lane >> 4;

    f32x4 acc0[4][4], acc1[4][4];
    const f32x4 vzero = {0.f, 0.f, 0.f, 0.f};
#pragma unroll
    for (int i = 0; i < 4; i++)
#pragma unroll
        for (int j = 0; j < 4; j++) { acc0[i][j] = vzero; acc1[i][j] = vzero; }

    const int sr = lane >> 3;
    const int csrc = ((lane & 7) ^ sr) * 8;

    for (int ee = 0; ee < 2; ee++) {
        const int e = g * 2 + ee;
        const u16* Ag  = fused + ((size_t)e * T_ + t0) * D_;
        const u16* Bg0 = wdT + ((size_t)e * H_ + h0) * D_;
        const u16* Bg1 = wdT + ((size_t)e * H_ + h0 + 128) * D_;
        for (int k0 = 0; k0 < D_; k0 += 64) {
#pragma unroll
            for (int c = 0; c < 4; c++) {
                const int R = wave * 32 + c * 8;
                const size_t go = (size_t)(R + sr) * D_ + k0 + csrc;
                gload16(Ag + go,  &As[R * 64]);
                gload16(Bg0 + go, &B0s[R * 64]);
                gload16(Bg1 + go, &B1s[R * 64]);
            }
            __syncthreads();
#pragma unroll
            for (int kk = 0; kk < 2; kk++) {
                const int pco = (((kk << 2) | quad) ^ (l16 & 7)) * 8;
                bf16x8 af[4], b0[4], b1[4];
#pragma unroll
                for (int i = 0; i < 4; i++)
                    af[i] = *(const bf16x8*)&As[(wr + i * 16 + l16) * 64 + pco];
#pragma unroll
                for (int j = 0; j < 4; j++) {
                    b0[j] = *(const bf16x8*)&B0s[(wc + j * 16 + l16) * 64 + pco];
                    b1[j] = *(const bf16x8*)&B1s[(wc + j * 16 + l16) * 64 + pco];
                }
#pragma unroll
                for (int i = 0; i < 4; i++)
#pragma unroll
                    for (int j = 0; j < 4; j++) {
                        acc0[i][j] = __builtin_amdgcn_mfma_f32_16x16x32_bf16(af[i], b0[j], acc0[i][j], 0, 0, 0);
                        acc1[i][j] = __builtin_amdgcn_mfma_f32_16x16x32_bf16(af[i], b1[j], acc1[i][j], 0, 0, 0);
                    }
            }
            __syncthreads();
        }
    }

    float* po = pout + (size_t)g * T_ * H_;
#pragma unroll
    for (int i = 0; i < 4; i++) {
#pragma unroll
        for (int r = 0; r < 4; r++) {
            int row = t0 + wr + i * 16 + quad * 4 + r;
#pragma unroll
            for (int j = 0; j < 4; j++) {
                int col0 = h0 + wc + j * 16 + l16;
                po[(size_t)row * H_ + col0]       = acc0[i][j][r];
                po[(size_t)row * H_ + col0 + 128] = acc1[i][j][r];
            }
        }
    }
}

// out[t][h] = sum_g pout[g] + sum_e rw[t][e] * down_b[e][h]
__global__ __launch_bounds__(256) void k_combine(const float* __restrict__ p,
                                                 const float* __restrict__ rw,
                                                 const float* __restrict__ db,
                                                 float* __restrict__ out) {
    int idx = blockIdx.x * 256 + threadIdx.x;  // exactly T_*H_ threads
    int t = idx >> 11;
    int h = idx & (H_ - 1);
    const size_t TH = (size_t)T_ * H_;
    float s = p[idx] + p[idx + TH] + p[idx + 2 * TH] + p[idx + 3 * TH];
#pragma unroll
    for (int e = 0; e < E_; e++) s += rw[t * E_ + e] * db[e * H_ + h];
    out[idx] = s;
}

// ---------------- launch ----------------

extern "C" void kernel_launch(void* const* d_in, const int* in_sizes, int n_in,
                              void* d_out, int out_size, void* d_ws, size_t ws_size,
                              hipStream_t stream) {
    const float* x   = (const float*)d_in[0];   // [B,S,H]
    const float* rw  = (const float*)d_in[1];   // [T,E]
    const float* guw = (const float*)d_in[2];   // [E,H,2D]
    const float* gub = (const float*)d_in[3];   // [E,2D]
    const float* dww = (const float*)d_in[4];   // [E,D,H]
    const float* dwb = (const float*)d_in[5];   // [E,H]
    float* out = (float*)d_out;

    char* ws = (char*)d_ws;
    u16* xb    = (u16*)(ws);                      //  8 MB  [T][H]
    u16* wgT   = (u16*)(ws + 8388608);            // 64 MB  [E][D][H]
    u16* wuT   = (u16*)(ws + 75497472);           // 64 MB  [E][D][H]
    u16* wdT   = (u16*)(ws + 142606336);          // 64 MB  [E][H][D]
    u16* fused = (u16*)(ws + 209715200);          // 64 MB  [E][T][D]
    // pout (64 MB fp32 [4][T][H]) reuses the wgT region — wgT is dead after
    // k_gemm_gateup, and the stream serializes gateup -> down -> combine.
    float* pout = (float*)(ws + 8388608);

    k_convert_x<<<dim3((T_ * H_) / 4 / 256), 256, 0, stream>>>((const float4*)x, (ushort4*)xb);
    k_tr_gateup<<<dim3(H_ / 64, D_ / 64, E_), 256, 0, stream>>>(guw, wgT, wuT);
    k_tr_down<<<dim3(D_ / 64, H_ / 64, E_), 256, 0, stream>>>(dww, wdT);
    k_gemm_gateup<<<dim3(T_ / 128, D_ / 128, E_), 256, 0, stream>>>(xb, wgT, wuT, gub, rw, fused);
    k_gemm_down<<<dim3(T_ / 128, H_ / 256, 4), 256, 0, stream>>>(fused, wdT, pout);
    k_combine<<<dim3((T_ * H_) / 256), 256, 0, stream>>>(pout, rw, dwb, out);
}

// Round 5
// 910.218 us; speedup vs baseline: 2.3958x; 1.0051x over previous
//
#include <hip/hip_runtime.h>
#include <hip/hip_bf16.h>

typedef unsigned short u16;
typedef __bf16 bf16x8 __attribute__((ext_vector_type(8)));
typedef float f32x4 __attribute__((ext_vector_type(4)));

#define E_ 8
#define H_ 2048
#define D_ 2048
#define T_ 2048
#define N2_ 4096

__device__ __forceinline__ u16 f2bf(float f) {
    unsigned u = __builtin_bit_cast(unsigned, f);
    unsigned r = (u + 0x7FFFu + ((u >> 16) & 1u)) >> 16;
    return (u16)r;
}

typedef __attribute__((address_space(1))) const void* gptr_t;
typedef __attribute__((address_space(3))) void* lptr_t;
__device__ __forceinline__ void gload16(const void* g, void* l) {
    // async global->LDS, 16B/lane; LDS dest = wave-uniform base + lane*16
    __builtin_amdgcn_global_load_lds((gptr_t)g, (lptr_t)l, 16, 0, 0);
}

// LDS tile layout (BK=64): 128 rows x 64 u16 (128B = 8 chunks of 16B).
// Physical chunk(r,c) stored at c ^ (r&7)  -> every ds_read_b128 fragment
// access is exactly 2-way bank-aliased (free; verified R3/R4: conflicts=0).
// Swizzle applied by permuting the global SOURCE address per lane during
// global_load_lds (dest order is fixed: base + lane*16).
//
// R3 post-mortem: __launch_bounds__(256,3) spills the 128-reg accumulator
// tile (1.5 GB scratch traffic, 3x slower). Keep the 2-wave/EU budget.
//
// R5: XCD-aware 1D grid swizzle. Dispatch assigns consecutive block IDs
// round-robin across the 8 XCDs (id&7). We map IDs so each XCD owns a
// fixed slice of B-tiles and the t-blocks sharing a B-tile run
// consecutively on the same XCD -> B-tile stays in that XCD's 4MB L2,
// cutting HBM re-fetch and (mainly) the vmcnt barrier-drain latency.

// ---------------- conversion / transpose pre-pass ----------------

__global__ __launch_bounds__(256) void k_convert_x(const float4* __restrict__ x,
                                                   ushort4* __restrict__ xb) {
    int i = blockIdx.x * 256 + threadIdx.x;   // exactly T_*H_/4 threads
    float4 v = x[i];
    ushort4 o;
    o.x = f2bf(v.x); o.y = f2bf(v.y); o.z = f2bf(v.z); o.w = f2bf(v.w);
    xb[i] = o;
}

// gate_up_w fp32 [E][H][2D] -> wgT,wuT bf16 [E][D][H]  (transpose + de-interleave)
__global__ __launch_bounds__(256) void k_tr_gateup(const float* __restrict__ w,
                                                   u16* __restrict__ wgT,
                                                   u16* __restrict__ wuT) {
    __shared__ u16 Gs[64 * 73];
    __shared__ u16 Us[64 * 73];
    const int e = blockIdx.z, h0 = blockIdx.x * 64, d0 = blockIdx.y * 64;
    const int tid = threadIdx.x;
    {
        const int hl = tid >> 2;               // 0..63
        const int cseg = (tid & 3) * 32;       // fp32 col offset within 128
        const float* src = w + ((size_t)e * H_ + h0 + hl) * N2_ + 2 * d0 + cseg;
#pragma unroll
        for (int q = 0; q < 8; q++) {
            float4 v = *(const float4*)(src + q * 4);
            int dl = (cseg + q * 4) >> 1;      // even
            Gs[hl * 73 + dl]     = f2bf(v.x);
            Us[hl * 73 + dl]     = f2bf(v.y);
            Gs[hl * 73 + dl + 1] = f2bf(v.z);
            Us[hl * 73 + dl + 1] = f2bf(v.w);
        }
    }
    __syncthreads();
    {
        const int dl = tid >> 2;
        const int hseg = (tid & 3) * 16;
        u16 vg[16] __attribute__((aligned(16)));
        u16 vu[16] __attribute__((aligned(16)));
#pragma unroll
        for (int j = 0; j < 16; j++) {
            vg[j] = Gs[(hseg + j) * 73 + dl];
            vu[j] = Us[(hseg + j) * 73 + dl];
        }
        size_t ob = ((size_t)e * D_ + d0 + dl) * H_ + h0 + hseg;
        *(uint4*)&wgT[ob]     = *(const uint4*)&vg[0];
        *(uint4*)&wgT[ob + 8] = *(const uint4*)&vg[8];
        *(uint4*)&wuT[ob]     = *(const uint4*)&vu[0];
        *(uint4*)&wuT[ob + 8] = *(const uint4*)&vu[8];
    }
}

// down_w fp32 [E][D][H] -> wdT bf16 [E][H][D]  (transpose)
__global__ __launch_bounds__(256) void k_tr_down(const float* __restrict__ w,
                                                 u16* __restrict__ wdT) {
    __shared__ u16 Ts[64 * 73];
    const int e = blockIdx.z, d0 = blockIdx.x * 64, h0 = blockIdx.y * 64;
    const int tid = threadIdx.x;
    {
        const int dl = tid >> 2;
        const int hseg = (tid & 3) * 16;
        const float* src = w + ((size_t)e * D_ + d0 + dl) * H_ + h0 + hseg;
#pragma unroll
        for (int q = 0; q < 4; q++) {
            float4 v = *(const float4*)(src + q * 4);
            int hl = hseg + q * 4;
            Ts[(hl + 0) * 73 + dl] = f2bf(v.x);
            Ts[(hl + 1) * 73 + dl] = f2bf(v.y);
            Ts[(hl + 2) * 73 + dl] = f2bf(v.z);
            Ts[(hl + 3) * 73 + dl] = f2bf(v.w);
        }
    }
    __syncthreads();
    {
        const int hl = tid >> 2;
        const int dseg = (tid & 3) * 16;
        u16 vd[16] __attribute__((aligned(16)));
#pragma unroll
        for (int j = 0; j < 16; j++) vd[j] = Ts[hl * 73 + dseg + j];
        size_t ob = ((size_t)e * H_ + h0 + hl) * D_ + d0 + dseg;
        *(uint4*)&wdT[ob]     = *(const uint4*)&vd[0];
        *(uint4*)&wdT[ob + 8] = *(const uint4*)&vd[8];
    }
}

// ---------------- GEMM 1: gate_up + GLU epilogue (rw folded in) ----------------
// fused[e][t][d] = rw[t][e] * (clip(up,-7,7)+1) * glu(min(gate,7))

__global__ __launch_bounds__(256, 2) void k_gemm_gateup(
    const u16* __restrict__ xb,    // [T][H] bf16
    const u16* __restrict__ wgT,   // [E][D][H] bf16
    const u16* __restrict__ wuT,   // [E][D][H] bf16
    const float* __restrict__ gub, // [E][2D] fp32 interleaved
    const float* __restrict__ rw,  // [T][E] fp32
    u16* __restrict__ fused)       // [E][T][D] bf16
{
    // XCD swizzle: grid = 2048 1D. XCD k (= id&7, dispatch round-robin) owns
    // d-tiles {2k,2k+1} for all e; within an XCD, t varies fastest so the 16
    // blocks sharing one (e,d) B-tile run back-to-back on the same XCD.
    const int id = blockIdx.x;
    const int xcd = id & 7;
    const int local = id >> 3;           // 0..255
    const int e = local >> 5;            // 0..7
    const int rem = local & 31;
    const int t0 = (rem & 15) * 128;
    const int d0 = (xcd * 2 + (rem >> 4)) * 128;

    __shared__ u16 As[128 * 64];
    __shared__ u16 Bgs[128 * 64];
    __shared__ u16 Bus[128 * 64];

    const int tid = threadIdx.x;
    const int lane = tid & 63;
    const int wave = tid >> 6;
    const int wr = (wave >> 1) * 64;
    const int wc = (wave & 1) * 64;
    const int l16 = lane & 15;
    const int quad = lane >> 4;

    f32x4 accg[4][4], accu[4][4];
    const f32x4 vzero = {0.f, 0.f, 0.f, 0.f};
#pragma unroll
    for (int i = 0; i < 4; i++)
#pragma unroll
        for (int j = 0; j < 4; j++) { accg[i][j] = vzero; accu[i][j] = vzero; }

    const u16* Ag  = xb + (size_t)t0 * H_;
    const u16* Bgg = wgT + ((size_t)e * D_ + d0) * H_;
    const u16* Bug = wuT + ((size_t)e * D_ + d0) * H_;

    // staging: one gload16 covers 8 rows x 64 u16; lane -> row R+(lane>>3),
    // physical chunk lane&7; source chunk = (lane&7) ^ (lane>>3)  [swizzle]
    const int sr = lane >> 3;
    const int csrc = ((lane & 7) ^ sr) * 8;   // u16 offset in row

    for (int k0 = 0; k0 < H_; k0 += 64) {
#pragma unroll
        for (int c = 0; c < 4; c++) {
            const int R = wave * 32 + c * 8;
            const size_t go = (size_t)(R + sr) * H_ + k0 + csrc;
            gload16(Ag + go,  &As[R * 64]);
            gload16(Bgg + go, &Bgs[R * 64]);
            gload16(Bug + go, &Bus[R * 64]);
        }
        __syncthreads();
#pragma unroll
        for (int kk = 0; kk < 2; kk++) {
            // fragment col (u16): physical chunk = (kk*4+quad) ^ (row&7); row&7 == l16&7
            const int pco = (((kk << 2) | quad) ^ (l16 & 7)) * 8;
            bf16x8 af[4], bg[4], bu[4];
#pragma unroll
            for (int i = 0; i < 4; i++)
                af[i] = *(const bf16x8*)&As[(wr + i * 16 + l16) * 64 + pco];
#pragma unroll
            for (int j = 0; j < 4; j++) {
                bg[j] = *(const bf16x8*)&Bgs[(wc + j * 16 + l16) * 64 + pco];
                bu[j] = *(const bf16x8*)&Bus[(wc + j * 16 + l16) * 64 + pco];
            }
#pragma unroll
            for (int i = 0; i < 4; i++)
#pragma unroll
                for (int j = 0; j < 4; j++) {
                    accg[i][j] = __builtin_amdgcn_mfma_f32_16x16x32_bf16(af[i], bg[j], accg[i][j], 0, 0, 0);
                    accu[i][j] = __builtin_amdgcn_mfma_f32_16x16x32_bf16(af[i], bu[j], accu[i][j], 0, 0, 0);
                }
        }
        __syncthreads();
    }

    // epilogue: bias + clamp + GLU, scale by routing weight, write bf16
#pragma unroll
    for (int j = 0; j < 4; j++) {
        const int col = d0 + wc + j * 16 + l16;
        const float bgv = gub[e * N2_ + 2 * col];
        const float buv = gub[e * N2_ + 2 * col + 1];
#pragma unroll
        for (int i = 0; i < 4; i++) {
#pragma unroll
            for (int r = 0; r < 4; r++) {
                int row = t0 + wr + i * 16 + quad * 4 + r;
                float g = accg[i][j][r] + bgv;
                float u = accu[i][j][r] + buv;
                g = fminf(g, 7.0f);
                u = fminf(fmaxf(u, -7.0f), 7.0f);
                float glu = g / (1.0f + __expf(-1.702f * g));
                float f = (u + 1.0f) * glu * rw[row * E_ + e];
                fused[((size_t)e * T_ + row) * D_ + col] = f2bf(f);
            }
        }
    }
}

// ---------------- GEMM 2: down proj, experts-in-K, 128x256 tile, no atomics ----
// pout[g][t][h] = sum_{e in pair g} fused[e][t][:] @ wdT[e][h][:]

__global__ __launch_bounds__(256, 2) void k_gemm_down(
    const u16* __restrict__ fused, // [E][T][D] bf16 (rw-scaled)
    const u16* __restrict__ wdT,   // [E][H][D] bf16
    float* __restrict__ pout)      // [4][T][H] fp32 partials
{
    // XCD swizzle: grid = 512 1D. XCD k owns h-tile k (256 cols); within an
    // XCD, t varies fastest for each expert-pair g -> the 16 blocks sharing
    // one (g,h) B-tile run concurrently on the same XCD.
    const int id = blockIdx.x;
    const int xcd = id & 7;
    const int local = id >> 3;          // 0..63
    const int g = local >> 4;           // expert pair: experts 2g, 2g+1
    const int t0 = (local & 15) * 128;
    const int h0 = xcd * 256;

    __shared__ u16 As[128 * 64];
    __shared__ u16 B0s[128 * 64];
    __shared__ u16 B1s[128 * 64];

    const int tid = threadIdx.x;
    const int lane = tid & 63;
    const int wave = tid >> 6;
    const int wr = (wave >> 1) * 64;
    const int wc = (wave & 1) * 64;
    const int l16 = lane & 15;
    const int quad = lane >> 4;

    f32x4 acc0[4][4], acc1[4][4];
    const f32x4 vzero = {0.f, 0.f, 0.f, 0.f};
#pragma unroll
    for (int i = 0; i < 4; i++)
#pragma unroll
        for (int j = 0; j < 4; j++) { acc0[i][j] = vzero; acc1[i][j] = vzero; }

    const int sr = lane >> 3;
    const int csrc = ((lane & 7) ^ sr) * 8;

    for (int ee = 0; ee < 2; ee++) {
        const int e = g * 2 + ee;
        const u16* Ag  = fused + ((size_t)e * T_ + t0) * D_;
        const u16* Bg0 = wdT + ((size_t)e * H_ + h0) * D_;
        const u16* Bg1 = wdT + ((size_t)e * H_ + h0 + 128) * D_;
        for (int k0 = 0; k0 < D_; k0 += 64) {
#pragma unroll
            for (int c = 0; c < 4; c++) {
                const int R = wave * 32 + c * 8;
                const size_t go = (size_t)(R + sr) * D_ + k0 + csrc;
                gload16(Ag + go,  &As[R * 64]);
                gload16(Bg0 + go, &B0s[R * 64]);
                gload16(Bg1 + go, &B1s[R * 64]);
            }
            __syncthreads();
#pragma unroll
            for (int kk = 0; kk < 2; kk++) {
                const int pco = (((kk << 2) | quad) ^ (l16 & 7)) * 8;
                bf16x8 af[4], b0[4], b1[4];
#pragma unroll
                for (int i = 0; i < 4; i++)
                    af[i] = *(const bf16x8*)&As[(wr + i * 16 + l16) * 64 + pco];
#pragma unroll
                for (int j = 0; j < 4; j++) {
                    b0[j] = *(const bf16x8*)&B0s[(wc + j * 16 + l16) * 64 + pco];
                    b1[j] = *(const bf16x8*)&B1s[(wc + j * 16 + l16) * 64 + pco];
                }
#pragma unroll
                for (int i = 0; i < 4; i++)
#pragma unroll
                    for (int j = 0; j < 4; j++) {
                        acc0[i][j] = __builtin_amdgcn_mfma_f32_16x16x32_bf16(af[i], b0[j], acc0[i][j], 0, 0, 0);
                        acc1[i][j] = __builtin_amdgcn_mfma_f32_16x16x32_bf16(af[i], b1[j], acc1[i][j], 0, 0, 0);
                    }
            }
            __syncthreads();
        }
    }

    float* po = pout + (size_t)g * T_ * H_;
#pragma unroll
    for (int i = 0; i < 4; i++) {
#pragma unroll
        for (int r = 0; r < 4; r++) {
            int row = t0 + wr + i * 16 + quad * 4 + r;
#pragma unroll
            for (int j = 0; j < 4; j++) {
                int col0 = h0 + wc + j * 16 + l16;
                po[(size_t)row * H_ + col0]       = acc0[i][j][r];
                po[(size_t)row * H_ + col0 + 128] = acc1[i][j][r];
            }
        }
    }
}

// out[t][h] = sum_g pout[g] + sum_e rw[t][e] * down_b[e][h]   (float4)
__global__ __launch_bounds__(256) void k_combine(const float4* __restrict__ p,
                                                 const float* __restrict__ rw,
                                                 const float4* __restrict__ db,
                                                 float4* __restrict__ out) {
    int i = blockIdx.x * 256 + threadIdx.x;   // T_*H_/4 elements
    int t = i >> 9;                            // H_/4 = 512 float4 per row
    int h4 = i & 511;
    const size_t TH4 = (size_t)T_ * H_ / 4;
    float4 s0 = p[i], s1 = p[i + TH4], s2 = p[i + 2 * TH4], s3 = p[i + 3 * TH4];
    float4 a;
    a.x = s0.x + s1.x + s2.x + s3.x;
    a.y = s0.y + s1.y + s2.y + s3.y;
    a.z = s0.z + s1.z + s2.z + s3.z;
    a.w = s0.w + s1.w + s2.w + s3.w;
#pragma unroll
    for (int e = 0; e < E_; e++) {
        float w = rw[t * E_ + e];
        float4 b = db[e * (H_ / 4) + h4];
        a.x += w * b.x; a.y += w * b.y; a.z += w * b.z; a.w += w * b.w;
    }
    out[i] = a;
}

// ---------------- launch ----------------

extern "C" void kernel_launch(void* const* d_in, const int* in_sizes, int n_in,
                              void* d_out, int out_size, void* d_ws, size_t ws_size,
                              hipStream_t stream) {
    const float* x   = (const float*)d_in[0];   // [B,S,H]
    const float* rw  = (const float*)d_in[1];   // [T,E]
    const float* guw = (const float*)d_in[2];   // [E,H,2D]
    const float* gub = (const float*)d_in[3];   // [E,2D]
    const float* dww = (const float*)d_in[4];   // [E,D,H]
    const float* dwb = (const float*)d_in[5];   // [E,H]
    float* out = (float*)d_out;

    char* ws = (char*)d_ws;
    u16* xb    = (u16*)(ws);                      //  8 MB  [T][H]
    u16* wgT   = (u16*)(ws + 8388608);            // 64 MB  [E][D][H]
    u16* wuT   = (u16*)(ws + 75497472);           // 64 MB  [E][D][H]
    u16* wdT   = (u16*)(ws + 142606336);          // 64 MB  [E][H][D]
    u16* fused = (u16*)(ws + 209715200);          // 64 MB  [E][T][D]
    // pout (64 MB fp32 [4][T][H]) reuses the wgT region — wgT is dead after
    // k_gemm_gateup, and the stream serializes gateup -> down -> combine.
    float* pout = (float*)(ws + 8388608);

    k_convert_x<<<dim3((T_ * H_) / 4 / 256), 256, 0, stream>>>((const float4*)x, (ushort4*)xb);
    k_tr_gateup<<<dim3(H_ / 64, D_ / 64, E_), 256, 0, stream>>>(guw, wgT, wuT);
    k_tr_down<<<dim3(D_ / 64, H_ / 64, E_), 256, 0, stream>>>(dww, wdT);
    k_gemm_gateup<<<dim3(2048), 256, 0, stream>>>(xb, wgT, wuT, gub, rw, fused);
    k_gemm_down<<<dim3(512), 256, 0, stream>>>(fused, wdT, pout);
    k_combine<<<dim3((T_ * H_) / 4 / 256), 256, 0, stream>>>((const float4*)pout, rw, (const float4*)dwb, (float4*)out);
}